// Round 4
// baseline (2820.195 us; speedup 1.0000x reference)
//
#include <hip/hip_runtime.h>
#include <hip/hip_bf16.h>
#include <climits>

#define NB 2
#define NPTS_ 16384
#define IMH 200
#define IMW 176
#define IMC 256
#define KTOT_ 2048
#define ROWS_ 4096
#define CIN_ 288
#define COUT_ 128

// ---------------------------------------------------------------- FPS: 6 blocks = (batch, band)
// Zero global scratch: compacted original indices live in LDS (u16); keypoints
// exit via out2 (fp32, exact).
__launch_bounds__(1024)
__global__ void k_fps(const float* __restrict__ pts, const float* __restrict__ rngv,
                      float* __restrict__ out2) {
#pragma clang fp contract(off)
  const int blk = blockIdx.x;
  const int band = blk % 3, batch = blk / 3;
  const int K = (band == 0) ? 1024 : 512;
  const int off = (band == 0) ? 0 : (band == 1 ? 1024 : 1536);
  const int base = batch * NPTS_;

  __shared__ unsigned short s_idx[NPTS_];               // 32 KB compacted -> original idx
  __shared__ float s_kx[1024], s_ky[1024], s_kz[1024];  // 12 KB selected keypoints
  __shared__ int s_wsum[16];
  __shared__ int s_woff[16];
  __shared__ int s_total;
  __shared__ float s_cd[2][16];
  __shared__ int s_cp[2][16];
  __shared__ float s_cx[2][16], s_cy[2][16], s_cz[2][16];

  const int tid = threadIdx.x, lane = tid & 63, wv = tid >> 6;

  // mask + count own contiguous 16-point chunk (order-preserving compaction)
  bool val[16];
  int cnt = 0;
  for (int j = 0; j < 16; ++j) {
    float r = rngv[base + tid * 16 + j];
    bool sm = (r > 0.0f) && (r < 25.0f);
    bool lm = (r > 45.0f);
    bool v = (band == 0) ? sm : (band == 2 ? lm : (!lm && !sm));
    val[j] = v;
    cnt += v ? 1 : 0;
  }
  // wave inclusive scan of per-thread counts
  int inc = cnt;
  for (int d = 1; d < 64; d <<= 1) {
    int o = __shfl_up(inc, d);
    if (lane >= d) inc += o;
  }
  if (lane == 63) s_wsum[wv] = inc;
  __syncthreads();
  if (tid == 0) {
    int acc = 0;
    for (int w = 0; w < 16; ++w) { s_woff[w] = acc; acc += s_wsum[w]; }
    s_total = acc;
  }
  __syncthreads();
  int myoff = s_woff[wv] + inc - cnt;
  for (int j = 0; j < 16; ++j) {
    if (val[j]) s_idx[myoff++] = (unsigned short)(tid * 16 + j);
  }
  __syncthreads();
  const int M = s_total;

  // strided ownership of compacted points; coords gathered from points (fp32)
  float lx[16], ly[16], lz[16], ld[16];
  int nloc = 0;
  for (int j = 0; j < 16; ++j) {
    int p = tid + (j << 10);
    if (p < M) {
      int gi = (base + (int)s_idx[p]) * 5;
      lx[j] = pts[gi + 1];
      ly[j] = pts[gi + 2];
      lz[j] = pts[gi + 3];
      ld[j] = 1e10f;
      nloc = j + 1;
    }
  }

  if (tid == 0) {
    int gi = (base + (int)s_idx[0]) * 5;
    s_kx[0] = pts[gi + 1];
    s_ky[0] = pts[gi + 2];
    s_kz[0] = pts[gi + 3];
  }
  __syncthreads();
  float lastx = s_kx[0], lasty = s_ky[0], lastz = s_kz[0];

  int bufc = 0;
  for (int k = 1; k < K; ++k) {
    float bd = -1.0f; int bp = INT_MAX;
    float bx = 0.f, by = 0.f, bz = 0.f;
    for (int j = 0; j < nloc; ++j) {
      float dx = lx[j] - lastx;
      float dy = ly[j] - lasty;
      float dz = lz[j] - lastz;
      float d = dx * dx;
      d += dy * dy;
      d += dz * dz;
      float nd = fminf(ld[j], d);
      ld[j] = nd;
      int p = tid + (j << 10);
      if (nd > bd || (nd == bd && p < bp)) { bd = nd; bp = p; bx = lx[j]; by = ly[j]; bz = lz[j]; }
    }
    // wave butterfly argmax (tie -> smallest compacted index), carrying coords
    for (int o = 32; o > 0; o >>= 1) {
      float od = __shfl_xor(bd, o); int op = __shfl_xor(bp, o);
      float ox = __shfl_xor(bx, o), oy = __shfl_xor(by, o), oz = __shfl_xor(bz, o);
      if (od > bd || (od == bd && op < bp)) { bd = od; bp = op; bx = ox; by = oy; bz = oz; }
    }
    if (lane == 0) {
      s_cd[bufc][wv] = bd; s_cp[bufc][wv] = bp;
      s_cx[bufc][wv] = bx; s_cy[bufc][wv] = by; s_cz[bufc][wv] = bz;
    }
    __syncthreads();
    int sl = lane & 15;
    float cd = s_cd[bufc][sl]; int cp = s_cp[bufc][sl];
    float cxx = s_cx[bufc][sl], cyy = s_cy[bufc][sl], czz = s_cz[bufc][sl];
    for (int o = 8; o > 0; o >>= 1) {
      float od = __shfl_xor(cd, o); int op = __shfl_xor(cp, o);
      float ox = __shfl_xor(cxx, o), oy = __shfl_xor(cyy, o), oz = __shfl_xor(czz, o);
      if (od > cd || (od == cd && op < cp)) { cd = od; cp = op; cxx = ox; cyy = oy; czz = oz; }
    }
    lastx = cxx; lasty = cyy; lastz = czz;
    if (tid == 0) { s_kx[k] = cxx; s_ky[k] = cyy; s_kz[k] = czz; }
    bufc ^= 1;
  }
  __syncthreads();
  const float batf = (float)batch;
  for (int i = tid; i < K; i += 1024) {
    int g = batch * KTOT_ + off + i;
    out2[g * 4 + 0] = batf;
    out2[g * 4 + 1] = s_kx[i];
    out2[g * 4 + 2] = s_ky[i];
    out2[g * 4 + 3] = s_kz[i];
  }
}

// ---------------------------------------------------------------- bilinear BEV gather, native [B,C,H,W]
__launch_bounds__(256)
__global__ void k_bev(const float* __restrict__ sf, const float* __restrict__ out2,
                      float* __restrict__ out1) {
#pragma clang fp contract(off)
  int tid = threadIdx.x, lane = tid & 63, wv = tid >> 6;
  int g = blockIdx.x * 4 + wv;
  if (g >= ROWS_) return;
  int b = g >> 11;
  float xx = out2[g * 4 + 1], yy = out2[g * 4 + 2];
  float x = (xx - 0.0f) / 0.05f / 8.0f;
  float y = (yy - (-40.0f)) / 0.05f / 8.0f;
  int x0 = (int)floorf(x), y0 = (int)floorf(y);
  int x1 = x0 + 1, y1 = y0 + 1;
  x0 = min(max(x0, 0), IMW - 1); x1 = min(max(x1, 0), IMW - 1);
  y0 = min(max(y0, 0), IMH - 1); y1 = min(max(y1, 0), IMH - 1);
  float x0f = (float)x0, x1f = (float)x1, y0f = (float)y0, y1f = (float)y1;
  float wa = (x1f - x) * (y1f - y);
  float wb = (x1f - x) * (y - y0f);
  float wc = (x - x0f) * (y1f - y);
  float wd = (x - x0f) * (y - y0f);
  int oa = y0 * IMW + x0;
  int ob = y1 * IMW + x0;
  int oc = y0 * IMW + x1;
  int od = y1 * IMW + x1;
  const float* pb = sf + (size_t)b * IMC * IMH * IMW;
  for (int j = 0; j < 4; ++j) {
    int c = lane * 4 + j;
    const float* pc = pb + (size_t)c * (IMH * IMW);
    float o = pc[oa] * wa;
    o += pc[ob] * wb;
    o += pc[oc] * wc;
    o += pc[od] * wd;
    out1[(size_t)g * CIN_ + c] = o;
  }
}

// ---------------------------------------------------------------- SA: ball query + MLP + maxpool (wave per kp)
__launch_bounds__(256)
__global__ void k_sa(const float* __restrict__ pts, const float* __restrict__ out2,
                     const float* __restrict__ w0, const float* __restrict__ bn0,
                     const float* __restrict__ w1, const float* __restrict__ bn1,
                     float* __restrict__ out1) {
#pragma clang fp contract(off)
  __shared__ float s_w0[128];   // [2][4][16]
  __shared__ float s_w1[512];   // [2][16][16]
  __shared__ float s_s0[32], s_m0[32], s_b0[32];  // [2][16]
  __shared__ float s_s1[32], s_m1[32], s_b1[32];
  int tid = threadIdx.x;
  for (int i = tid; i < 128; i += 256) s_w0[i] = w0[i];
  for (int i = tid; i < 512; i += 256) s_w1[i] = w1[i];
  if (tid < 32) {
    int rad = tid >> 4, c = tid & 15;
    int bb = rad * 64;
    {
      float gg = bn0[bb + c], bbt = bn0[bb + 16 + c];
      float mm = bn0[bb + 32 + c], vv = bn0[bb + 48 + c];
      s_s0[tid] = gg / sqrtf(vv + 1e-5f); s_m0[tid] = mm; s_b0[tid] = bbt;
    }
    {
      float gg = bn1[bb + c], bbt = bn1[bb + 16 + c];
      float mm = bn1[bb + 32 + c], vv = bn1[bb + 48 + c];
      s_s1[tid] = gg / sqrtf(vv + 1e-5f); s_m1[tid] = mm; s_b1[tid] = bbt;
    }
  }
  __syncthreads();

  int lane = tid & 63, wv = tid >> 6;
  int g = blockIdx.x * 4 + wv;
  if (g >= ROWS_) return;
  int batch = g >> 11;
  int base = batch * NPTS_;
  float kx = out2[g * 4 + 1];
  float ky = out2[g * 4 + 2];
  float kz = out2[g * 4 + 3];

  int myrad = (lane >> 4) & 1, myslot = lane & 15;
  int c1 = 0, c2 = 0, first1 = -1, first2 = -1, myidx = -1;
  for (int r = 0; r < NPTS_ / 64; ++r) {
    int gi = (base + r * 64 + lane) * 5;
    float dx = kx - pts[gi + 1];
    float dy = ky - pts[gi + 2];
    float dz = kz - pts[gi + 3];
    float d = dx * dx;
    d += dy * dy;
    d += dz * dz;
    unsigned long long m1 = __ballot(d < 1.0f);
    unsigned long long m2 = __ballot(d < 4.0f);
    while (m1 && c1 < 16) {
      int bpos = __builtin_ctzll(m1); m1 &= m1 - 1;
      int pi = r * 64 + bpos;
      if (c1 == 0) first1 = pi;
      if (lane < 32 && myrad == 0 && c1 == myslot) myidx = pi;
      ++c1;
    }
    while (m2 && c2 < 16) {
      int bpos = __builtin_ctzll(m2); m2 &= m2 - 1;
      int pi = r * 64 + bpos;
      if (c2 == 0) first2 = pi;
      if (lane < 32 && myrad == 1 && c2 == myslot) myidx = pi;
      ++c2;
    }
    if (c1 >= 16 && c2 >= 16) break;
  }
  int fi = (myrad == 0) ? first1 : first2;
  bool use = (lane < 32) && (fi >= 0);
  if (myidx < 0) myidx = (fi >= 0) ? fi : 0;
  float gx = 0.f, gy = 0.f, gz = 0.f, gf = 0.f;
  if (use) {
    int gi = (base + myidx) * 5;
    gx = pts[gi + 1] - kx;
    gy = pts[gi + 2] - ky;
    gz = pts[gi + 3] - kz;
    gf = pts[gi + 4];
  }
  const float* W0 = s_w0 + myrad * 64;    // [4][16]
  const float* W1 = s_w1 + myrad * 256;   // [16][16]
  int bc = myrad * 16;
  float h1[16];
  for (int c = 0; c < 16; ++c) {
    float a = gx * W0[c];
    a += gy * W0[16 + c];
    a += gz * W0[32 + c];
    a += gf * W0[48 + c];
    h1[c] = fmaxf((a - s_m0[bc + c]) * s_s0[bc + c] + s_b0[bc + c], 0.f);
  }
  for (int c = 0; c < 16; ++c) {
    float a = 0.f;
    for (int k = 0; k < 16; ++k) a += h1[k] * W1[k * 16 + c];
    float h2 = fmaxf((a - s_m1[bc + c]) * s_s1[bc + c] + s_b1[bc + c], 0.f);
    h2 = fmaxf(h2, __shfl_xor(h2, 1));
    h2 = fmaxf(h2, __shfl_xor(h2, 2));
    h2 = fmaxf(h2, __shfl_xor(h2, 4));
    h2 = fmaxf(h2, __shfl_xor(h2, 8));
    if (lane < 32 && myslot == 0) {
      int col = 256 + myrad * 16 + c;
      out1[(size_t)g * CIN_ + col] = h2;
    }
  }
}

// ---------------------------------------------------------------- fusion: [4096,288]@[288,128] + BN + ReLU
__launch_bounds__(128)
__global__ void k_fuse(const float* __restrict__ out1, const float* __restrict__ fw,
                       const float* __restrict__ fbn, float* __restrict__ out0) {
  int r = blockIdx.x, c = threadIdx.x;
  __shared__ float sA[CIN_];
  for (int i = c; i < CIN_; i += 128) sA[i] = out1[(size_t)r * CIN_ + i];
  __syncthreads();
  float acc = 0.f;
  for (int k = 0; k < CIN_; ++k) acc += sA[k] * fw[k * COUT_ + c];
  float gg = fbn[c], bb = fbn[COUT_ + c];
  float mm = fbn[2 * COUT_ + c], vv = fbn[3 * COUT_ + c];
  float sc = gg / sqrtf(vv + 1e-5f);
  float o = fmaxf((acc - mm) * sc + bb, 0.f);
  out0[(size_t)r * COUT_ + c] = o;
}

// ---------------------------------------------------------------- launch (ZERO d_ws usage)
extern "C" void kernel_launch(void* const* d_in, const int* in_sizes, int n_in,
                              void* d_out, int out_size, void* d_ws, size_t ws_size,
                              hipStream_t stream) {
  const float* points = (const float*)d_in[0];
  const float* rng    = (const float*)d_in[1];
  const float* sf     = (const float*)d_in[2];
  const float* w0     = (const float*)d_in[3];
  const float* bn0    = (const float*)d_in[4];
  const float* w1     = (const float*)d_in[5];
  const float* bn1    = (const float*)d_in[6];
  const float* fw     = (const float*)d_in[7];
  const float* fbn    = (const float*)d_in[8];

  float* out0 = (float*)d_out;                         // fused [4096,128]
  float* out1 = out0 + (size_t)ROWS_ * COUT_;          // feats [4096,288]
  float* out2 = out1 + (size_t)ROWS_ * CIN_;           // point_coords [4096,4]

  k_fps<<<6, 1024, 0, stream>>>(points, rng, out2);
  k_bev<<<ROWS_ / 4, 256, 0, stream>>>(sf, out2, out1);
  k_sa<<<ROWS_ / 4, 256, 0, stream>>>(points, out2, w0, bn0, w1, bn1, out1);
  k_fuse<<<ROWS_, 128, 0, stream>>>(out1, fw, fbn, out0);
}

// Round 5
// 2214.091 us; speedup vs baseline: 1.2737x; 1.2737x over previous
//
#include <hip/hip_runtime.h>
#include <hip/hip_bf16.h>
#include <climits>

#define NB 2
#define NPTS_ 16384
#define IMH 200
#define IMW 176
#define IMC 256
#define KTOT_ 2048
#define ROWS_ 4096
#define CIN_ 288
#define COUT_ 128

// ---------------------------------------------------------------- FPS: 6 blocks = (batch, band)
// 256 threads (4 waves, 1/SIMD). Compacted indices in LDS (u16); up to 32
// owned points per thread in registers; one barrier per step; keypoints
// streamed to out2 by tid0.
__launch_bounds__(256, 1)
__global__ void k_fps(const float* __restrict__ pts, const float* __restrict__ rngv,
                      float* __restrict__ out2) {
#pragma clang fp contract(off)
  const int blk = blockIdx.x;
  const int band = blk % 3, batch = blk / 3;
  const int K = (band == 0) ? 1024 : 512;
  const int off = (band == 0) ? 0 : (band == 1 ? 1024 : 1536);
  const int base = batch * NPTS_;

  __shared__ unsigned short s_idx[NPTS_];   // 32 KB compacted -> original idx
  __shared__ int s_wsum[4];
  __shared__ float s_cd[2][4];
  __shared__ int s_cp[2][4];
  __shared__ float s_cx[2][4], s_cy[2][4], s_cz[2][4];

  const int tid = threadIdx.x, lane = tid & 63, wv = tid >> 6;

  // ---- mask own contiguous 64-point chunk into a bitmask (order-preserving)
  unsigned long long vm = 0ull;
  for (int j = 0; j < 64; ++j) {
    float r = rngv[base + tid * 64 + j];
    bool sm = (r > 0.0f) && (r < 25.0f);
    bool lm = (r > 45.0f);
    bool v = (band == 0) ? sm : (band == 2 ? lm : (!lm && !sm));
    vm |= (v ? 1ull : 0ull) << j;
  }
  int cnt = __popcll(vm);
  // wave inclusive scan of per-thread counts
  int inc = cnt;
  for (int d = 1; d < 64; d <<= 1) {
    int o = __shfl_up(inc, d);
    if (lane >= d) inc += o;
  }
  if (lane == 63) s_wsum[wv] = inc;
  __syncthreads();
  int woff = 0;
  for (int w = 0; w < wv; ++w) woff += s_wsum[w];
  const int M = s_wsum[0] + s_wsum[1] + s_wsum[2] + s_wsum[3];
  int myoff = woff + inc - cnt;
  unsigned long long t = vm;
  while (t) {
    int b = __builtin_ctzll(t);
    t &= t - 1;
    s_idx[myoff++] = (unsigned short)(tid * 64 + b);
  }
  __syncthreads();

  // ---- gather owned compacted points into registers (strided ownership)
  float lx[32], ly[32], lz[32], ld[32];
  int nloc = 0;
  for (int j = 0; j < 32; ++j) {
    int p = tid + (j << 8);
    if (p < M) {
      int gi = (base + (int)s_idx[p]) * 5;
      lx[j] = pts[gi + 1];
      ly[j] = pts[gi + 2];
      lz[j] = pts[gi + 3];
      ld[j] = 1e10f;
      nloc = j + 1;
    }
  }

  // ---- first keypoint = first valid (smallest original index)
  float lastx, lasty, lastz;
  {
    int gi = (base + (int)s_idx[0]) * 5;
    lastx = pts[gi + 1];
    lasty = pts[gi + 2];
    lastz = pts[gi + 3];
  }
  const float batf = (float)batch;
  if (tid == 0) {
    int g = batch * KTOT_ + off;
    out2[g * 4 + 0] = batf;
    out2[g * 4 + 1] = lastx;
    out2[g * 4 + 2] = lasty;
    out2[g * 4 + 3] = lastz;
  }

  int bufc = 0;
  for (int k = 1; k < K; ++k) {
    // scan: update running min-dist, track per-thread argmax (ascending p -> strict >)
    float bd = -1.0f; int bp = INT_MAX;
    float bx = 0.f, by = 0.f, bz = 0.f;
    for (int j = 0; j < nloc; ++j) {
      float dx = lx[j] - lastx;
      float dy = ly[j] - lasty;
      float dz = lz[j] - lastz;
      float d = dx * dx;
      d += dy * dy;
      d += dz * dz;
      float nd = fminf(ld[j], d);
      ld[j] = nd;
      if (nd > bd) { bd = nd; bp = tid + (j << 8); bx = lx[j]; by = ly[j]; bz = lz[j]; }
    }
    // wave butterfly argmax (tie -> smallest compacted index), carrying coords
    for (int o = 32; o > 0; o >>= 1) {
      float od = __shfl_xor(bd, o); int op = __shfl_xor(bp, o);
      float ox = __shfl_xor(bx, o), oy = __shfl_xor(by, o), oz = __shfl_xor(bz, o);
      if (od > bd || (od == bd && op < bp)) { bd = od; bp = op; bx = ox; by = oy; bz = oz; }
    }
    if (lane == 0) {
      s_cd[bufc][wv] = bd; s_cp[bufc][wv] = bp;
      s_cx[bufc][wv] = bx; s_cy[bufc][wv] = by; s_cz[bufc][wv] = bz;
    }
    __syncthreads();
    // all threads: sequential reduce over the 4 wave candidates (broadcast LDS reads)
    float cd = s_cd[bufc][0]; int cp = s_cp[bufc][0];
    float cxx = s_cx[bufc][0], cyy = s_cy[bufc][0], czz = s_cz[bufc][0];
    for (int w = 1; w < 4; ++w) {
      float od = s_cd[bufc][w]; int op = s_cp[bufc][w];
      if (od > cd || (od == cd && op < cp)) {
        cd = od; cp = op;
        cxx = s_cx[bufc][w]; cyy = s_cy[bufc][w]; czz = s_cz[bufc][w];
      }
    }
    lastx = cxx; lasty = cyy; lastz = czz;
    if (tid == 0) {
      int g = batch * KTOT_ + off + k;
      out2[g * 4 + 0] = batf;
      out2[g * 4 + 1] = cxx;
      out2[g * 4 + 2] = cyy;
      out2[g * 4 + 3] = czz;
    }
    bufc ^= 1;
  }
}

// ---------------------------------------------------------------- bilinear BEV gather, native [B,C,H,W]
__launch_bounds__(256)
__global__ void k_bev(const float* __restrict__ sf, const float* __restrict__ out2,
                      float* __restrict__ out1) {
#pragma clang fp contract(off)
  int tid = threadIdx.x, lane = tid & 63, wv = tid >> 6;
  int g = blockIdx.x * 4 + wv;
  if (g >= ROWS_) return;
  int b = g >> 11;
  float xx = out2[g * 4 + 1], yy = out2[g * 4 + 2];
  float x = (xx - 0.0f) / 0.05f / 8.0f;
  float y = (yy - (-40.0f)) / 0.05f / 8.0f;
  int x0 = (int)floorf(x), y0 = (int)floorf(y);
  int x1 = x0 + 1, y1 = y0 + 1;
  x0 = min(max(x0, 0), IMW - 1); x1 = min(max(x1, 0), IMW - 1);
  y0 = min(max(y0, 0), IMH - 1); y1 = min(max(y1, 0), IMH - 1);
  float x0f = (float)x0, x1f = (float)x1, y0f = (float)y0, y1f = (float)y1;
  float wa = (x1f - x) * (y1f - y);
  float wb = (x1f - x) * (y - y0f);
  float wc = (x - x0f) * (y1f - y);
  float wd = (x - x0f) * (y - y0f);
  int oa = y0 * IMW + x0;
  int ob = y1 * IMW + x0;
  int oc = y0 * IMW + x1;
  int od = y1 * IMW + x1;
  const float* pb = sf + (size_t)b * IMC * IMH * IMW;
  for (int j = 0; j < 4; ++j) {
    int c = lane * 4 + j;
    const float* pc = pb + (size_t)c * (IMH * IMW);
    float o = pc[oa] * wa;
    o += pc[ob] * wb;
    o += pc[oc] * wc;
    o += pc[od] * wd;
    out1[(size_t)g * CIN_ + c] = o;
  }
}

// ---------------------------------------------------------------- SA: ball query + MLP + maxpool (wave per kp)
__launch_bounds__(256)
__global__ void k_sa(const float* __restrict__ pts, const float* __restrict__ out2,
                     const float* __restrict__ w0, const float* __restrict__ bn0,
                     const float* __restrict__ w1, const float* __restrict__ bn1,
                     float* __restrict__ out1) {
#pragma clang fp contract(off)
  __shared__ float s_w0[128];   // [2][4][16]
  __shared__ float s_w1[512];   // [2][16][16]
  __shared__ float s_s0[32], s_m0[32], s_b0[32];  // [2][16]
  __shared__ float s_s1[32], s_m1[32], s_b1[32];
  int tid = threadIdx.x;
  for (int i = tid; i < 128; i += 256) s_w0[i] = w0[i];
  for (int i = tid; i < 512; i += 256) s_w1[i] = w1[i];
  if (tid < 32) {
    int rad = tid >> 4, c = tid & 15;
    int bb = rad * 64;
    {
      float gg = bn0[bb + c], bbt = bn0[bb + 16 + c];
      float mm = bn0[bb + 32 + c], vv = bn0[bb + 48 + c];
      s_s0[tid] = gg / sqrtf(vv + 1e-5f); s_m0[tid] = mm; s_b0[tid] = bbt;
    }
    {
      float gg = bn1[bb + c], bbt = bn1[bb + 16 + c];
      float mm = bn1[bb + 32 + c], vv = bn1[bb + 48 + c];
      s_s1[tid] = gg / sqrtf(vv + 1e-5f); s_m1[tid] = mm; s_b1[tid] = bbt;
    }
  }
  __syncthreads();

  int lane = tid & 63, wv = tid >> 6;
  int g = blockIdx.x * 4 + wv;
  if (g >= ROWS_) return;
  int batch = g >> 11;
  int base = batch * NPTS_;
  float kx = out2[g * 4 + 1];
  float ky = out2[g * 4 + 2];
  float kz = out2[g * 4 + 3];

  int myrad = (lane >> 4) & 1, myslot = lane & 15;
  int c1 = 0, c2 = 0, first1 = -1, first2 = -1, myidx = -1;
  for (int r = 0; r < NPTS_ / 64; ++r) {
    int gi = (base + r * 64 + lane) * 5;
    float dx = kx - pts[gi + 1];
    float dy = ky - pts[gi + 2];
    float dz = kz - pts[gi + 3];
    float d = dx * dx;
    d += dy * dy;
    d += dz * dz;
    unsigned long long m1 = __ballot(d < 1.0f);
    unsigned long long m2 = __ballot(d < 4.0f);
    while (m1 && c1 < 16) {
      int bpos = __builtin_ctzll(m1); m1 &= m1 - 1;
      int pi = r * 64 + bpos;
      if (c1 == 0) first1 = pi;
      if (lane < 32 && myrad == 0 && c1 == myslot) myidx = pi;
      ++c1;
    }
    while (m2 && c2 < 16) {
      int bpos = __builtin_ctzll(m2); m2 &= m2 - 1;
      int pi = r * 64 + bpos;
      if (c2 == 0) first2 = pi;
      if (lane < 32 && myrad == 1 && c2 == myslot) myidx = pi;
      ++c2;
    }
    if (c1 >= 16 && c2 >= 16) break;
  }
  int fi = (myrad == 0) ? first1 : first2;
  bool use = (lane < 32) && (fi >= 0);
  if (myidx < 0) myidx = (fi >= 0) ? fi : 0;
  float gx = 0.f, gy = 0.f, gz = 0.f, gf = 0.f;
  if (use) {
    int gi = (base + myidx) * 5;
    gx = pts[gi + 1] - kx;
    gy = pts[gi + 2] - ky;
    gz = pts[gi + 3] - kz;
    gf = pts[gi + 4];
  }
  const float* W0 = s_w0 + myrad * 64;    // [4][16]
  const float* W1 = s_w1 + myrad * 256;   // [16][16]
  int bc = myrad * 16;
  float h1[16];
  for (int c = 0; c < 16; ++c) {
    float a = gx * W0[c];
    a += gy * W0[16 + c];
    a += gz * W0[32 + c];
    a += gf * W0[48 + c];
    h1[c] = fmaxf((a - s_m0[bc + c]) * s_s0[bc + c] + s_b0[bc + c], 0.f);
  }
  for (int c = 0; c < 16; ++c) {
    float a = 0.f;
    for (int k = 0; k < 16; ++k) a += h1[k] * W1[k * 16 + c];
    float h2 = fmaxf((a - s_m1[bc + c]) * s_s1[bc + c] + s_b1[bc + c], 0.f);
    h2 = fmaxf(h2, __shfl_xor(h2, 1));
    h2 = fmaxf(h2, __shfl_xor(h2, 2));
    h2 = fmaxf(h2, __shfl_xor(h2, 4));
    h2 = fmaxf(h2, __shfl_xor(h2, 8));
    if (lane < 32 && myslot == 0) {
      int col = 256 + myrad * 16 + c;
      out1[(size_t)g * CIN_ + col] = h2;
    }
  }
}

// ---------------------------------------------------------------- fusion: [4096,288]@[288,128] + BN + ReLU
__launch_bounds__(128)
__global__ void k_fuse(const float* __restrict__ out1, const float* __restrict__ fw,
                       const float* __restrict__ fbn, float* __restrict__ out0) {
  int r = blockIdx.x, c = threadIdx.x;
  __shared__ float sA[CIN_];
  for (int i = c; i < CIN_; i += 128) sA[i] = out1[(size_t)r * CIN_ + i];
  __syncthreads();
  float acc = 0.f;
  for (int k = 0; k < CIN_; ++k) acc += sA[k] * fw[k * COUT_ + c];
  float gg = fbn[c], bb = fbn[COUT_ + c];
  float mm = fbn[2 * COUT_ + c], vv = fbn[3 * COUT_ + c];
  float sc = gg / sqrtf(vv + 1e-5f);
  float o = fmaxf((acc - mm) * sc + bb, 0.f);
  out0[(size_t)r * COUT_ + c] = o;
}

// ---------------------------------------------------------------- launch (ZERO d_ws usage)
extern "C" void kernel_launch(void* const* d_in, const int* in_sizes, int n_in,
                              void* d_out, int out_size, void* d_ws, size_t ws_size,
                              hipStream_t stream) {
  const float* points = (const float*)d_in[0];
  const float* rng    = (const float*)d_in[1];
  const float* sf     = (const float*)d_in[2];
  const float* w0     = (const float*)d_in[3];
  const float* bn0    = (const float*)d_in[4];
  const float* w1     = (const float*)d_in[5];
  const float* bn1    = (const float*)d_in[6];
  const float* fw     = (const float*)d_in[7];
  const float* fbn    = (const float*)d_in[8];

  float* out0 = (float*)d_out;                         // fused [4096,128]
  float* out1 = out0 + (size_t)ROWS_ * COUT_;          // feats [4096,288]
  float* out2 = out1 + (size_t)ROWS_ * CIN_;           // point_coords [4096,4]

  k_fps<<<6, 256, 0, stream>>>(points, rng, out2);
  k_bev<<<ROWS_ / 4, 256, 0, stream>>>(sf, out2, out1);
  k_sa<<<ROWS_ / 4, 256, 0, stream>>>(points, out2, w0, bn0, w1, bn1, out1);
  k_fuse<<<ROWS_, 128, 0, stream>>>(out1, fw, fbn, out0);
}

// Round 6
// 1531.738 us; speedup vs baseline: 1.8412x; 1.4455x over previous
//
#include <hip/hip_runtime.h>
#include <hip/hip_bf16.h>
#include <climits>

#define NB 2
#define NPTS_ 16384
#define IMH 200
#define IMW 176
#define IMC 256
#define KTOT_ 2048
#define ROWS_ 4096
#define CIN_ 288
#define COUT_ 128

// ---------------------------------------------------------------- FPS core (templated slot count -> true VGPR arrays)
template <int NL>
__device__ __forceinline__ void fps_core(
    int tid, int lane, int wv, int M, int K, int base,
    const float* __restrict__ pts,
    const unsigned short* __restrict__ s_idx,
    float4* __restrict__ s_k,
    float2 (* __restrict__ s_cdp)[4],
    float4 (* __restrict__ s_cxyz)[4]) {
#pragma clang fp contract(off)
  float lx[NL], ly[NL], lz[NL], ld[NL];
#pragma unroll
  for (int j = 0; j < NL; ++j) {
    int p = tid + (j << 8);
    bool v = p < M;
    int oi = v ? (int)s_idx[p] : 0;
    int gi = (base + oi) * 5;
    lx[j] = pts[gi + 1];
    ly[j] = pts[gi + 2];
    lz[j] = pts[gi + 3];
    ld[j] = v ? 1e10f : -1.0f;   // invalid slots pinned at -1: never selected
  }
  // first keypoint = first valid (smallest original index)
  int gi0 = (base + (int)s_idx[0]) * 5;
  float lastx = pts[gi0 + 1], lasty = pts[gi0 + 2], lastz = pts[gi0 + 3];
  if (tid == 0) s_k[0] = make_float4(lastx, lasty, lastz, 0.f);

  int bufc = 0;
  for (int k = 1; k < K; ++k) {
    // phase 1+2: update running min-dist, per-thread argmax chain
    // (p ascends with j, so strict > == first-index tie-break)
    float bd = -1.0f; int bj = 0;
    float bx = lx[0], by = ly[0], bz = lz[0];
#pragma unroll
    for (int j = 0; j < NL; ++j) {
      float dx = lx[j] - lastx;
      float dy = ly[j] - lasty;
      float dz = lz[j] - lastz;
      float d = dx * dx;
      d += dy * dy;
      d += dz * dz;
      float nd = fminf(ld[j], d);
      ld[j] = nd;
      if (nd > bd) { bd = nd; bj = j; bx = lx[j]; by = ly[j]; bz = lz[j]; }
    }
    int bp = tid + (bj << 8);
    // wave butterfly on (d, p) only; tie -> smallest compacted index p
    for (int o = 32; o > 0; o >>= 1) {
      float od = __shfl_xor(bd, o);
      int op = __shfl_xor(bp, o);
      if (od > bd || (od == bd && op < bp)) { bd = od; bp = op; }
    }
    // winner coords via 3 broadcast shuffles from the winning lane
    int wl = bp & 63;
    float wx = __shfl(bx, wl);
    float wy = __shfl(by, wl);
    float wz = __shfl(bz, wl);
    if (lane == 0) {
      s_cdp[bufc][wv] = make_float2(bd, __int_as_float(bp));
      s_cxyz[bufc][wv] = make_float4(wx, wy, wz, 0.f);
    }
    __syncthreads();
    // all threads reduce the 4 wave candidates (broadcast LDS b64 reads)
    float2 c0 = s_cdp[bufc][0];
    float cd = c0.x; int cp = __float_as_int(c0.y); int cw = 0;
    for (int w = 1; w < 4; ++w) {
      float2 cc = s_cdp[bufc][w];
      float od = cc.x; int op = __float_as_int(cc.y);
      if (od > cd || (od == cd && op < cp)) { cd = od; cp = op; cw = w; }
    }
    float4 kk = s_cxyz[bufc][cw];
    lastx = kk.x; lasty = kk.y; lastz = kk.z;
    if (tid == 0) s_k[k] = kk;
    bufc ^= 1;
  }
}

// ---------------------------------------------------------------- FPS: 6 blocks = (batch, band), 256 threads
__launch_bounds__(256, 1)
__global__ void k_fps(const float* __restrict__ pts, const float* __restrict__ rngv,
                      float* __restrict__ out2) {
#pragma clang fp contract(off)
  const int blk = blockIdx.x;
  const int band = blk % 3, batch = blk / 3;
  const int K = (band == 0) ? 1024 : 512;
  const int off = (band == 0) ? 0 : (band == 1 ? 1024 : 1536);
  const int base = batch * NPTS_;

  __shared__ unsigned short s_idx[NPTS_];   // 32 KB compacted -> original idx
  __shared__ float4 s_k[1024];              // 16 KB selected keypoints
  __shared__ float2 s_cdp[2][4];
  __shared__ float4 s_cxyz[2][4];
  __shared__ int s_wsum[4];

  const int tid = threadIdx.x, lane = tid & 63, wv = tid >> 6;

  // ---- mask own contiguous 64-point chunk into a bitmask (order-preserving)
  unsigned long long vm = 0ull;
  for (int j = 0; j < 64; ++j) {
    float r = rngv[base + tid * 64 + j];
    bool sm = (r > 0.0f) && (r < 25.0f);
    bool lm = (r > 45.0f);
    bool v = (band == 0) ? sm : (band == 2 ? lm : (!lm && !sm));
    vm |= (v ? 1ull : 0ull) << j;
  }
  int cnt = __popcll(vm);
  int inc = cnt;
  for (int d = 1; d < 64; d <<= 1) {
    int o = __shfl_up(inc, d);
    if (lane >= d) inc += o;
  }
  if (lane == 63) s_wsum[wv] = inc;
  __syncthreads();
  int woff = 0;
  for (int w = 0; w < wv; ++w) woff += s_wsum[w];
  const int M = s_wsum[0] + s_wsum[1] + s_wsum[2] + s_wsum[3];
  int myoff = woff + inc - cnt;
  unsigned long long t = vm;
  while (t) {
    int b = __builtin_ctzll(t);
    t &= t - 1;
    s_idx[myoff++] = (unsigned short)(tid * 64 + b);
  }
  __syncthreads();

  // ---- dispatch to size-specialized serial loop (arrays in VGPRs)
  int nl = (M + 255) >> 8;
  if (nl <= 12)      fps_core<12>(tid, lane, wv, M, K, base, pts, s_idx, s_k, s_cdp, s_cxyz);
  else if (nl <= 16) fps_core<16>(tid, lane, wv, M, K, base, pts, s_idx, s_k, s_cdp, s_cxyz);
  else if (nl <= 24) fps_core<24>(tid, lane, wv, M, K, base, pts, s_idx, s_k, s_cdp, s_cxyz);
  else               fps_core<32>(tid, lane, wv, M, K, base, pts, s_idx, s_k, s_cdp, s_cxyz);

  // ---- epilogue: stream keypoints to out2
  __syncthreads();
  const float batf = (float)batch;
  for (int i = tid; i < K; i += 256) {
    int g = (batch * KTOT_ + off + i) * 4;
    float4 kk = s_k[i];
    out2[g + 0] = batf;
    out2[g + 1] = kk.x;
    out2[g + 2] = kk.y;
    out2[g + 3] = kk.z;
  }
}

// ---------------------------------------------------------------- bilinear BEV gather, native [B,C,H,W]
__launch_bounds__(256)
__global__ void k_bev(const float* __restrict__ sf, const float* __restrict__ out2,
                      float* __restrict__ out1) {
#pragma clang fp contract(off)
  int tid = threadIdx.x, lane = tid & 63, wv = tid >> 6;
  int g = blockIdx.x * 4 + wv;
  if (g >= ROWS_) return;
  int b = g >> 11;
  float xx = out2[g * 4 + 1], yy = out2[g * 4 + 2];
  float x = (xx - 0.0f) / 0.05f / 8.0f;
  float y = (yy - (-40.0f)) / 0.05f / 8.0f;
  int x0 = (int)floorf(x), y0 = (int)floorf(y);
  int x1 = x0 + 1, y1 = y0 + 1;
  x0 = min(max(x0, 0), IMW - 1); x1 = min(max(x1, 0), IMW - 1);
  y0 = min(max(y0, 0), IMH - 1); y1 = min(max(y1, 0), IMH - 1);
  float x0f = (float)x0, x1f = (float)x1, y0f = (float)y0, y1f = (float)y1;
  float wa = (x1f - x) * (y1f - y);
  float wb = (x1f - x) * (y - y0f);
  float wc = (x - x0f) * (y1f - y);
  float wd = (x - x0f) * (y - y0f);
  int oa = y0 * IMW + x0;
  int ob = y1 * IMW + x0;
  int oc = y0 * IMW + x1;
  int od = y1 * IMW + x1;
  const float* pb = sf + (size_t)b * IMC * IMH * IMW;
  for (int j = 0; j < 4; ++j) {
    int c = lane * 4 + j;
    const float* pc = pb + (size_t)c * (IMH * IMW);
    float o = pc[oa] * wa;
    o += pc[ob] * wb;
    o += pc[oc] * wc;
    o += pc[od] * wd;
    out1[(size_t)g * CIN_ + c] = o;
  }
}

// ---------------------------------------------------------------- SA: ball query + MLP + maxpool (wave per kp)
__launch_bounds__(256)
__global__ void k_sa(const float* __restrict__ pts, const float* __restrict__ out2,
                     const float* __restrict__ w0, const float* __restrict__ bn0,
                     const float* __restrict__ w1, const float* __restrict__ bn1,
                     float* __restrict__ out1) {
#pragma clang fp contract(off)
  __shared__ float s_w0[128];   // [2][4][16]
  __shared__ float s_w1[512];   // [2][16][16]
  __shared__ float s_s0[32], s_m0[32], s_b0[32];  // [2][16]
  __shared__ float s_s1[32], s_m1[32], s_b1[32];
  int tid = threadIdx.x;
  for (int i = tid; i < 128; i += 256) s_w0[i] = w0[i];
  for (int i = tid; i < 512; i += 256) s_w1[i] = w1[i];
  if (tid < 32) {
    int rad = tid >> 4, c = tid & 15;
    int bb = rad * 64;
    {
      float gg = bn0[bb + c], bbt = bn0[bb + 16 + c];
      float mm = bn0[bb + 32 + c], vv = bn0[bb + 48 + c];
      s_s0[tid] = gg / sqrtf(vv + 1e-5f); s_m0[tid] = mm; s_b0[tid] = bbt;
    }
    {
      float gg = bn1[bb + c], bbt = bn1[bb + 16 + c];
      float mm = bn1[bb + 32 + c], vv = bn1[bb + 48 + c];
      s_s1[tid] = gg / sqrtf(vv + 1e-5f); s_m1[tid] = mm; s_b1[tid] = bbt;
    }
  }
  __syncthreads();

  int lane = tid & 63, wv = tid >> 6;
  int g = blockIdx.x * 4 + wv;
  if (g >= ROWS_) return;
  int batch = g >> 11;
  int base = batch * NPTS_;
  float kx = out2[g * 4 + 1];
  float ky = out2[g * 4 + 2];
  float kz = out2[g * 4 + 3];

  int myrad = (lane >> 4) & 1, myslot = lane & 15;
  int c1 = 0, c2 = 0, first1 = -1, first2 = -1, myidx = -1;
  for (int r = 0; r < NPTS_ / 64; ++r) {
    int gi = (base + r * 64 + lane) * 5;
    float dx = kx - pts[gi + 1];
    float dy = ky - pts[gi + 2];
    float dz = kz - pts[gi + 3];
    float d = dx * dx;
    d += dy * dy;
    d += dz * dz;
    unsigned long long m1 = __ballot(d < 1.0f);
    unsigned long long m2 = __ballot(d < 4.0f);
    while (m1 && c1 < 16) {
      int bpos = __builtin_ctzll(m1); m1 &= m1 - 1;
      int pi = r * 64 + bpos;
      if (c1 == 0) first1 = pi;
      if (lane < 32 && myrad == 0 && c1 == myslot) myidx = pi;
      ++c1;
    }
    while (m2 && c2 < 16) {
      int bpos = __builtin_ctzll(m2); m2 &= m2 - 1;
      int pi = r * 64 + bpos;
      if (c2 == 0) first2 = pi;
      if (lane < 32 && myrad == 1 && c2 == myslot) myidx = pi;
      ++c2;
    }
    if (c1 >= 16 && c2 >= 16) break;
  }
  int fi = (myrad == 0) ? first1 : first2;
  bool use = (lane < 32) && (fi >= 0);
  if (myidx < 0) myidx = (fi >= 0) ? fi : 0;
  float gx = 0.f, gy = 0.f, gz = 0.f, gf = 0.f;
  if (use) {
    int gi = (base + myidx) * 5;
    gx = pts[gi + 1] - kx;
    gy = pts[gi + 2] - ky;
    gz = pts[gi + 3] - kz;
    gf = pts[gi + 4];
  }
  const float* W0 = s_w0 + myrad * 64;    // [4][16]
  const float* W1 = s_w1 + myrad * 256;   // [16][16]
  int bc = myrad * 16;
  float h1[16];
  for (int c = 0; c < 16; ++c) {
    float a = gx * W0[c];
    a += gy * W0[16 + c];
    a += gz * W0[32 + c];
    a += gf * W0[48 + c];
    h1[c] = fmaxf((a - s_m0[bc + c]) * s_s0[bc + c] + s_b0[bc + c], 0.f);
  }
  for (int c = 0; c < 16; ++c) {
    float a = 0.f;
    for (int k = 0; k < 16; ++k) a += h1[k] * W1[k * 16 + c];
    float h2 = fmaxf((a - s_m1[bc + c]) * s_s1[bc + c] + s_b1[bc + c], 0.f);
    h2 = fmaxf(h2, __shfl_xor(h2, 1));
    h2 = fmaxf(h2, __shfl_xor(h2, 2));
    h2 = fmaxf(h2, __shfl_xor(h2, 4));
    h2 = fmaxf(h2, __shfl_xor(h2, 8));
    if (lane < 32 && myslot == 0) {
      int col = 256 + myrad * 16 + c;
      out1[(size_t)g * CIN_ + col] = h2;
    }
  }
}

// ---------------------------------------------------------------- fusion: [4096,288]@[288,128] + BN + ReLU
__launch_bounds__(128)
__global__ void k_fuse(const float* __restrict__ out1, const float* __restrict__ fw,
                       const float* __restrict__ fbn, float* __restrict__ out0) {
  int r = blockIdx.x, c = threadIdx.x;
  __shared__ float sA[CIN_];
  for (int i = c; i < CIN_; i += 128) sA[i] = out1[(size_t)r * CIN_ + i];
  __syncthreads();
  float acc = 0.f;
  for (int k = 0; k < CIN_; ++k) acc += sA[k] * fw[k * COUT_ + c];
  float gg = fbn[c], bb = fbn[COUT_ + c];
  float mm = fbn[2 * COUT_ + c], vv = fbn[3 * COUT_ + c];
  float sc = gg / sqrtf(vv + 1e-5f);
  float o = fmaxf((acc - mm) * sc + bb, 0.f);
  out0[(size_t)r * COUT_ + c] = o;
}

// ---------------------------------------------------------------- launch (ZERO d_ws usage)
extern "C" void kernel_launch(void* const* d_in, const int* in_sizes, int n_in,
                              void* d_out, int out_size, void* d_ws, size_t ws_size,
                              hipStream_t stream) {
  const float* points = (const float*)d_in[0];
  const float* rng    = (const float*)d_in[1];
  const float* sf     = (const float*)d_in[2];
  const float* w0     = (const float*)d_in[3];
  const float* bn0    = (const float*)d_in[4];
  const float* w1     = (const float*)d_in[5];
  const float* bn1    = (const float*)d_in[6];
  const float* fw     = (const float*)d_in[7];
  const float* fbn    = (const float*)d_in[8];

  float* out0 = (float*)d_out;                         // fused [4096,128]
  float* out1 = out0 + (size_t)ROWS_ * COUT_;          // feats [4096,288]
  float* out2 = out1 + (size_t)ROWS_ * CIN_;           // point_coords [4096,4]

  k_fps<<<6, 256, 0, stream>>>(points, rng, out2);
  k_bev<<<ROWS_ / 4, 256, 0, stream>>>(sf, out2, out1);
  k_sa<<<ROWS_ / 4, 256, 0, stream>>>(points, out2, w0, bn0, w1, bn1, out1);
  k_fuse<<<ROWS_, 128, 0, stream>>>(out1, fw, fbn, out0);
}